// Round 1
// baseline (845.681 us; speedup 1.0000x reference)
//
#include <hip/hip_runtime.h>
#include <math.h>

#ifndef M_PI
#define M_PI 3.14159265358979323846
#endif

// Detect whether the neighbors buffer is int32 or int64.
// If int64: values are in [0, 2^31), so every high 32-bit word (odd index,
// little-endian) is 0. If int32: odd words are random indices in [0, N);
// 1024 consecutive odd words all being zero has probability ~0.
__global__ void detect_idx_width(const unsigned* __restrict__ words,
                                 int* __restrict__ flag) {
    if (blockIdx.x == 0 && threadIdx.x == 0) {
        int is64 = 1;
#pragma unroll 1
        for (int k = 1; k < 2048; k += 2) {
            if (words[k] != 0u) { is64 = 0; break; }
        }
        *flag = is64;
    }
}

__global__ __launch_bounds__(256) void xsph_edge_kernel(
    const float* __restrict__ fc_p,
    const float* __restrict__ area,
    const float* __restrict__ density,
    const float* __restrict__ restDensity,
    const float* __restrict__ velocity,
    const float* __restrict__ rad,
    const void* __restrict__ nbr,
    const float* __restrict__ support_p,
    const int* __restrict__ flag,
    float* __restrict__ out,
    int E)
{
    const int is64 = *flag;                 // uniform scalar load
    const float fc = fc_p[0];
    const float h = support_p[0];
    const float C = 7.0f / ((float)M_PI * h * h);

    const long long e0 =
        (long long)(blockIdx.x * (long long)blockDim.x + threadIdx.x) * 4;
    if (e0 >= (long long)E) return;

    int ii[4], jj[4];
    if (is64) {
        const long long* ni = (const long long*)nbr;
        const long long* nj = ni + E;
#pragma unroll
        for (int k = 0; k < 4; ++k) {
            ii[k] = (int)ni[e0 + k];
            jj[k] = (int)nj[e0 + k];
        }
    } else {
        const int* ni = (const int*)nbr;
        const int* nj = ni + E;
        int4 iv = *(const int4*)(ni + e0);
        int4 jv = *(const int4*)(nj + e0);
        ii[0] = iv.x; ii[1] = iv.y; ii[2] = iv.z; ii[3] = iv.w;
        jj[0] = jv.x; jj[1] = jv.y; jj[2] = jv.z; jj[3] = jv.w;
    }

    float4 qv = *(const float4*)(rad + e0);
    float qq[4] = {qv.x, qv.y, qv.z, qv.w};

#pragma unroll
    for (int k = 0; k < 4; ++k) {
        const int i = ii[k];
        const int j = jj[k];
        const float rDi = restDensity[i];
        const float rDj = restDensity[j];
        const float fac = fc * rDj * area[j];
        const float rho_i = density[i] * rDi;
        const float rho_j = density[j] * rDj;
        const float2 vi = *(const float2*)(velocity + 2 * i);
        const float2 vj = *(const float2*)(velocity + 2 * j);
        const float q = qq[k];
        const float b = fmaxf(1.0f - q, 0.0f);
        const float b2 = b * b;
        const float w = C * (b2 * b2) * fmaf(4.0f, q, 1.0f);
        const float s = fac * 2.0f * w / (rho_i + rho_j);
        unsafeAtomicAdd(&out[2 * i],     s * (vj.x - vi.x));
        unsafeAtomicAdd(&out[2 * i + 1], s * (vj.y - vi.y));
    }
}

extern "C" void kernel_launch(void* const* d_in, const int* in_sizes, int n_in,
                              void* d_out, int out_size, void* d_ws, size_t ws_size,
                              hipStream_t stream) {
    const float* fc          = (const float*)d_in[0];
    const float* area        = (const float*)d_in[1];
    const float* density     = (const float*)d_in[2];
    const float* restDensity = (const float*)d_in[3];
    const float* velocity    = (const float*)d_in[4];
    const float* rad         = (const float*)d_in[5];
    const void*  nbr         = d_in[6];
    const float* support     = (const float*)d_in[7];
    float* out = (float*)d_out;
    int*   flag = (int*)d_ws;

    const int E = in_sizes[5];

    // Harness poisons d_out once and never re-poisons between replays:
    // zero it ourselves every call (graph-capture-safe).
    hipMemsetAsync(d_out, 0, (size_t)out_size * sizeof(float), stream);

    detect_idx_width<<<1, 1, 0, stream>>>((const unsigned*)nbr, flag);

    const int threads = 256;
    const long long nthreads = ((long long)E + 3) / 4;
    const int blocks = (int)((nthreads + threads - 1) / threads);
    xsph_edge_kernel<<<blocks, threads, 0, stream>>>(
        fc, area, density, restDensity, velocity, rad, nbr, support, flag,
        out, E);
}

// Round 2
// 219.284 us; speedup vs baseline: 3.8566x; 3.8566x over previous
//
#include <hip/hip_runtime.h>
#include <math.h>

#ifndef M_PI
#define M_PI 3.14159265358979323846
#endif

#define NBLK 512   // blocks (chunks) for count/scatter passes
#define BSZ  512   // particles per bucket
#define BSH  9     // log2(BSZ)

// ---------------------------------------------------------------- detect ----
// neighbors dtype probe: int64 => odd 32-bit words (high halves) are all 0.
__global__ void detect_idx_width(const unsigned* __restrict__ words,
                                 int* __restrict__ flag) {
    if (blockIdx.x == 0 && threadIdx.x == 0) {
        int is64 = 1;
#pragma unroll 1
        for (int k = 1; k < 2048; k += 2) {
            if (words[k] != 0u) { is64 = 0; break; }
        }
        *flag = is64;
    }
}

// ------------------------------------------------------------- pre table ----
// pre[p] = { fc*restDensity*area, density*restDensity, vel.x, vel.y }
__global__ __launch_bounds__(256) void precompute_particle(
    const float* __restrict__ fc_p, const float* __restrict__ area,
    const float* __restrict__ density, const float* __restrict__ restDensity,
    const float* __restrict__ velocity, float4* __restrict__ pre, int N)
{
    int p = blockIdx.x * 256 + threadIdx.x;
    if (p >= N) return;
    const float fc = fc_p[0];
    const float rD = restDensity[p];
    const float2 v = ((const float2*)velocity)[p];
    pre[p] = make_float4(fc * rD * area[p], density[p] * rD, v.x, v.y);
}

// ----------------------------------------------------------------- count ----
__global__ __launch_bounds__(256) void pass_count(
    const void* __restrict__ nbr, const int* __restrict__ flag,
    unsigned* __restrict__ table, int E, int NBnum)
{
    __shared__ unsigned cnt[1024];
    for (int t = threadIdx.x; t < NBnum; t += 256) cnt[t] = 0u;
    __syncthreads();
    const int is64 = *flag;
    const long long chunk = ((long long)E + NBLK - 1) / NBLK;
    const long long s = (long long)blockIdx.x * chunk;
    long long e = s + chunk; if (e > E) e = E;
    if (is64) {
        const long long* ni = (const long long*)nbr;
        for (long long idx = s + threadIdx.x; idx < e; idx += 256) {
            int i = (int)ni[idx];
            atomicAdd(&cnt[i >> BSH], 1u);
        }
    } else {
        const int* ni = (const int*)nbr;
        for (long long idx = s + threadIdx.x; idx < e; idx += 256) {
            int i = ni[idx];
            atomicAdd(&cnt[i >> BSH], 1u);
        }
    }
    __syncthreads();
    for (int t = threadIdx.x; t < NBnum; t += 256)
        table[(size_t)t * NBLK + blockIdx.x] = cnt[t];
}

// ------------------------------------------------- scan within bucket row ---
// grid = NBnum blocks of NBLK threads; in-place exclusive scan of each row,
// row total -> btot[row].
__global__ __launch_bounds__(NBLK) void scan_blocks(
    unsigned* __restrict__ table, unsigned* __restrict__ btot)
{
    __shared__ unsigned buf[NBLK];
    const int t = threadIdx.x;
    const size_t row = (size_t)blockIdx.x * NBLK;
    buf[t] = table[row + t];
    __syncthreads();
    for (int off = 1; off < NBLK; off <<= 1) {
        unsigned v = (t >= off) ? buf[t - off] : 0u;
        __syncthreads();
        buf[t] += v;
        __syncthreads();
    }
    table[row + t] = (t == 0) ? 0u : buf[t - 1];
    if (t == NBLK - 1) btot[blockIdx.x] = buf[t];
}

// -------------------------------------------------- scan bucket totals ------
// 1 block of NBnum threads (NBnum <= 1024). bstart[NBnum] = E sentinel.
__global__ void scan_buckets(const unsigned* __restrict__ btot,
                             unsigned* __restrict__ bstart, int NBnum)
{
    __shared__ unsigned buf[1024];
    const int t = threadIdx.x;
    buf[t] = btot[t];
    __syncthreads();
    for (int off = 1; off < NBnum; off <<= 1) {
        unsigned v = (t >= off) ? buf[t - off] : 0u;
        __syncthreads();
        buf[t] += v;
        __syncthreads();
    }
    bstart[t] = (t == 0) ? 0u : buf[t - 1];
    if (t == NBnum - 1) bstart[NBnum] = buf[t];
}

// --------------------------------------------------------------- scatter ----
// payload.x = j | (i_local << 22)   (requires N <= 2^22), payload.y = bits(q)
__global__ __launch_bounds__(256) void pass_scatter(
    const void* __restrict__ nbr, const float* __restrict__ rad,
    const int* __restrict__ flag, const unsigned* __restrict__ table,
    const unsigned* __restrict__ bstart, int2* __restrict__ jq,
    int E, int NBnum)
{
    __shared__ unsigned cur[1024];
    for (int t = threadIdx.x; t < NBnum; t += 256)
        cur[t] = bstart[t] + table[(size_t)t * NBLK + blockIdx.x];
    __syncthreads();
    const int is64 = *flag;
    const long long chunk = ((long long)E + NBLK - 1) / NBLK;
    const long long s = (long long)blockIdx.x * chunk;
    long long e = s + chunk; if (e > E) e = E;
    if (is64) {
        const long long* ni = (const long long*)nbr;
        const long long* nj = ni + E;
        for (long long idx = s + threadIdx.x; idx < e; idx += 256) {
            int i = (int)ni[idx];
            int j = (int)nj[idx];
            float q = rad[idx];
            unsigned pos = atomicAdd(&cur[i >> BSH], 1u);
            jq[pos] = make_int2(j | ((i & (BSZ - 1)) << 22), __float_as_int(q));
        }
    } else {
        const int* ni = (const int*)nbr;
        const int* nj = ni + E;
        for (long long idx = s + threadIdx.x; idx < e; idx += 256) {
            int i = ni[idx];
            int j = nj[idx];
            float q = rad[idx];
            unsigned pos = atomicAdd(&cur[i >> BSH], 1u);
            jq[pos] = make_int2(j | ((i & (BSZ - 1)) << 22), __float_as_int(q));
        }
    }
}

// ---------------------------------------------------------------- reduce ----
__global__ __launch_bounds__(256) void pass_reduce(
    const int2* __restrict__ jq, const float4* __restrict__ pre,
    const unsigned* __restrict__ bstart, const float* __restrict__ support_p,
    float2* __restrict__ out, int N)
{
    __shared__ float4 plds[BSZ];
    __shared__ float2 acc[BSZ];
    const int k = blockIdx.x;
    const int base = k << BSH;
    for (int t = threadIdx.x; t < BSZ; t += 256) {
        int p = base + t;
        plds[t] = (p < N) ? pre[p] : make_float4(0.f, 0.f, 0.f, 0.f);
        acc[t] = make_float2(0.f, 0.f);
    }
    __syncthreads();
    const float h = support_p[0];
    const float C = 7.0f / ((float)M_PI * h * h);
    const unsigned s = bstart[k];
    const unsigned e = bstart[k + 1];
    for (unsigned idx = s + threadIdx.x; idx < e; idx += 256) {
        const int2 pk = jq[idx];
        const int j = pk.x & ((1 << 22) - 1);
        const int il = (pk.x >> 22) & (BSZ - 1);
        const float q = __int_as_float(pk.y);
        const float4 pj = pre[j];
        const float4 pi = plds[il];
        const float b = fmaxf(1.0f - q, 0.0f);
        const float b2 = b * b;
        const float w = C * (b2 * b2) * fmaf(4.0f, q, 1.0f);
        const float sc = pj.x * 2.0f * w / (pi.y + pj.y);
        atomicAdd(&acc[il].x, sc * (pj.z - pi.z));
        atomicAdd(&acc[il].y, sc * (pj.w - pi.w));
    }
    __syncthreads();
    for (int t = threadIdx.x; t < BSZ; t += 256) {
        int p = base + t;
        if (p < N) out[p] = acc[t];
    }
}

// ------------------------------------------------- fallback (round-1 path) --
__global__ __launch_bounds__(256) void xsph_edge_kernel(
    const float* __restrict__ fc_p, const float* __restrict__ area,
    const float* __restrict__ density, const float* __restrict__ restDensity,
    const float* __restrict__ velocity, const float* __restrict__ rad,
    const void* __restrict__ nbr, const float* __restrict__ support_p,
    const int* __restrict__ flag, float* __restrict__ out, int E)
{
    const int is64 = *flag;
    const float fc = fc_p[0];
    const float h = support_p[0];
    const float C = 7.0f / ((float)M_PI * h * h);
    const long long e0 =
        (long long)(blockIdx.x * (long long)blockDim.x + threadIdx.x) * 4;
    if (e0 >= (long long)E) return;
    int ii[4], jj[4];
    if (is64) {
        const long long* ni = (const long long*)nbr;
        const long long* nj = ni + E;
#pragma unroll
        for (int k = 0; k < 4; ++k) { ii[k] = (int)ni[e0 + k]; jj[k] = (int)nj[e0 + k]; }
    } else {
        const int* ni = (const int*)nbr;
        const int* nj = ni + E;
        int4 iv = *(const int4*)(ni + e0);
        int4 jv = *(const int4*)(nj + e0);
        ii[0] = iv.x; ii[1] = iv.y; ii[2] = iv.z; ii[3] = iv.w;
        jj[0] = jv.x; jj[1] = jv.y; jj[2] = jv.z; jj[3] = jv.w;
    }
    float4 qv = *(const float4*)(rad + e0);
    float qq[4] = {qv.x, qv.y, qv.z, qv.w};
#pragma unroll
    for (int k = 0; k < 4; ++k) {
        const int i = ii[k], j = jj[k];
        const float rDi = restDensity[i], rDj = restDensity[j];
        const float fac = fc * rDj * area[j];
        const float rho_i = density[i] * rDi, rho_j = density[j] * rDj;
        const float2 vi = *(const float2*)(velocity + 2 * i);
        const float2 vj = *(const float2*)(velocity + 2 * j);
        const float q = qq[k];
        const float b = fmaxf(1.0f - q, 0.0f);
        const float b2 = b * b;
        const float w = C * (b2 * b2) * fmaf(4.0f, q, 1.0f);
        const float s = fac * 2.0f * w / (rho_i + rho_j);
        unsafeAtomicAdd(&out[2 * i],     s * (vj.x - vi.x));
        unsafeAtomicAdd(&out[2 * i + 1], s * (vj.y - vi.y));
    }
}

// ------------------------------------------------------------------ host ----
extern "C" void kernel_launch(void* const* d_in, const int* in_sizes, int n_in,
                              void* d_out, int out_size, void* d_ws, size_t ws_size,
                              hipStream_t stream) {
    const float* fc          = (const float*)d_in[0];
    const float* area        = (const float*)d_in[1];
    const float* density     = (const float*)d_in[2];
    const float* restDensity = (const float*)d_in[3];
    const float* velocity    = (const float*)d_in[4];
    const float* rad         = (const float*)d_in[5];
    const void*  nbr         = d_in[6];
    const float* support     = (const float*)d_in[7];

    const int N = in_sizes[1];
    const int E = in_sizes[5];
    const int NBnum = (N + BSZ - 1) / BSZ;

    // ---- workspace layout (16B-aligned sections) ----
    char* ws = (char*)d_ws;
    size_t off = 0;
    int* flag = (int*)(ws + off);               off += 16;
    float4* pre = (float4*)(ws + off);          off += (size_t)N * 16;
    unsigned* table = (unsigned*)(ws + off);    off += (size_t)NBnum * NBLK * 4;
    off = (off + 15) & ~(size_t)15;
    unsigned* btot = (unsigned*)(ws + off);     off += (size_t)NBnum * 4;
    off = (off + 15) & ~(size_t)15;
    unsigned* bstart = (unsigned*)(ws + off);   off += (size_t)(NBnum + 1) * 4;
    off = (off + 15) & ~(size_t)15;
    int2* jq = (int2*)(ws + off);               off += (size_t)E * 8;
    const size_t need = off;

    detect_idx_width<<<1, 1, 0, stream>>>((const unsigned*)nbr, flag);

    const bool can_sort =
        (ws_size >= need) && (NBnum <= 1024) && (N <= (1 << 22)) && (E > 0);

    if (can_sort) {
        precompute_particle<<<(N + 255) / 256, 256, 0, stream>>>(
            fc, area, density, restDensity, velocity, pre, N);
        pass_count<<<NBLK, 256, 0, stream>>>(nbr, flag, table, E, NBnum);
        scan_blocks<<<NBnum, NBLK, 0, stream>>>(table, btot);
        scan_buckets<<<1, NBnum, 0, stream>>>(btot, bstart, NBnum);
        pass_scatter<<<NBLK, 256, 0, stream>>>(nbr, rad, flag, table, bstart,
                                               jq, E, NBnum);
        pass_reduce<<<NBnum, 256, 0, stream>>>(jq, pre, bstart, support,
                                               (float2*)d_out, N);
    } else {
        hipMemsetAsync(d_out, 0, (size_t)out_size * sizeof(float), stream);
        const int threads = 256;
        const long long nthreads = ((long long)E + 3) / 4;
        const int blocks = (int)((nthreads + threads - 1) / threads);
        xsph_edge_kernel<<<blocks, threads, 0, stream>>>(
            fc, area, density, restDensity, velocity, rad, nbr, support, flag,
            (float*)d_out, E);
    }
}